// Round 5
// baseline (358.927 us; speedup 1.0000x reference)
//
#include <hip/hip_runtime.h>
#include <hip/hip_bf16.h>

// Problem constants
#define Bb 8
#define Ss 8192
#define Dd 256             // DIN == DH == 256
#define Mm (Bb * Ss)       // 65536 rows
#define Nn 512             // 2*DH output cols of the GEMM
#define NCHUNK 128
#define CLEN (Ss / NCHUNK) // 64

typedef __hip_bfloat16 bf16;
typedef __attribute__((ext_vector_type(8))) short short8;
typedef __attribute__((ext_vector_type(4))) float f32x4;

// ---------------------------------------------------------------------------
// f32 -> bf16 convert (vectorized float4 -> 4x bf16) — weights only now
// ---------------------------------------------------------------------------
__global__ __launch_bounds__(256) void cvt_f32_bf16(const float* __restrict__ in,
                                                    bf16* __restrict__ out,
                                                    long n4) {
  long i = (long)blockIdx.x * blockDim.x + threadIdx.x;
  if (i >= n4) return;
  const float4 v = ((const float4*)in)[i];
  union { ushort4 u; bf16 h[4]; } o;
  o.h[0] = __float2bfloat16(v.x);
  o.h[1] = __float2bfloat16(v.y);
  o.h[2] = __float2bfloat16(v.z);
  o.h[3] = __float2bfloat16(v.w);
  ((ushort4*)out)[i] = o.u;
}

// ---------------------------------------------------------------------------
// Pointwise: a = sigmoid(-gate), v = sigmoid(gate) * g(hidden)
// ---------------------------------------------------------------------------
__device__ __forceinline__ void av_from_gh(float gate, float hid, float& a,
                                           float& v) {
  gate = fminf(fmaxf(gate, -20.f), 20.f);
  float eg = __expf(gate);
  a = 1.f / (1.f + eg);   // sigmoid(-gate) = 1 - z
  float z = eg * a;       // sigmoid(gate)
  float gfun;
  if (hid >= 0.f) {
    gfun = hid + 0.5f;
  } else {
    float eh = __expf(fmaxf(hid, -20.f));
    gfun = eh / (1.f + eh);  // sigmoid(hid)
  }
  v = z * gfun;
}

__device__ __forceinline__ unsigned pack_av(float a, float v) {
  union { bf16 h[2]; unsigned u; } o;
  o.h[0] = __float2bfloat16(a);
  o.h[1] = __float2bfloat16(v);
  return o.u;
}

// Fragment loaders: MFMA 16x16x32 A/B layout, lane(fl,q) reads 8 contiguous
// k-elements at row*256 + k0 + q*8. 16B (bf16) / 32B (f32) aligned.
__device__ __forceinline__ short8 ld_frag_bf16(const bf16* p) {
  return *(const short8*)p;
}
__device__ __forceinline__ short8 ld_frag_f32(const float* p) {
  const float4 a = ((const float4*)p)[0];
  const float4 b = ((const float4*)p)[1];
  const float vals[8] = {a.x, a.y, a.z, a.w, b.x, b.y, b.z, b.w};
  short8 r;
#pragma unroll
  for (int i = 0; i < 8; i++) {
    union { bf16 h; short s; } t;
    t.h = __float2bfloat16(vals[i]);
    r[i] = t.s;
  }
  return r;
}

// ---------------------------------------------------------------------------
// Fused GEMM + bias + pointwise, NO LDS: fragments loaded straight from
// global (X via HBM/L3, W via L2) in MFMA layout; compiler pipelines the 64
// independent 16B loads across the fully-unrolled K loop (no barriers).
//   block (cb, bt): rows [bt*128,+128), paired channels d in [cb*64,+64)
// Writes AV[m*256 + d] = pack(a, v) bf16x2.
// ---------------------------------------------------------------------------
template <bool F32A>
__global__ __launch_bounds__(256) void gemm_av(const void* __restrict__ Xv,
                                               const bf16* __restrict__ W,
                                               const float* __restrict__ bias,
                                               unsigned* __restrict__ AV) {
  const int tid = threadIdx.x;
  const int w = tid >> 6;        // wave 0..3
  const int l = tid & 63;
  const int fl = l & 15;
  const int q = l >> 4;          // quad 0..3

  const int cb = blockIdx.x;     // paired-channel block 0..3
  const long rowBase = (long)blockIdx.y * 128;

  const int wrow = (w >> 1) * 64;
  const int wc = (w & 1) * 32;   // wave's channel offset within the 64

  // B row pointers (gate rows cb*64+wc+16p+fl; hidden rows +256)
  const bf16* Bg = W + (long)(cb * 64 + wc + fl) * 256 + q * 8;

  f32x4 acc[4][4];
#pragma unroll
  for (int i = 0; i < 4; i++)
#pragma unroll
    for (int j = 0; j < 4; j++) acc[i][j] = (f32x4)0.0f;

  const long arow = (rowBase + wrow + fl) * 256 + q * 8;

#pragma unroll
  for (int ks = 0; ks < 8; ks++) {
    const int k0 = ks * 32;
    short8 af[4], bfr[4];
#pragma unroll
    for (int mt = 0; mt < 4; mt++) {
      if (F32A)
        af[mt] = ld_frag_f32((const float*)Xv + arow + (long)mt * 16 * 256 + k0);
      else
        af[mt] = ld_frag_bf16((const bf16*)Xv + arow + (long)mt * 16 * 256 + k0);
    }
    bfr[0] = ld_frag_bf16(Bg + k0);
    bfr[1] = ld_frag_bf16(Bg + 16 * 256 + k0);
    bfr[2] = ld_frag_bf16(Bg + 256 * 256 + k0);
    bfr[3] = ld_frag_bf16(Bg + (256 + 16) * 256 + k0);

#pragma unroll
    for (int mt = 0; mt < 4; mt++)
#pragma unroll
      for (int nt = 0; nt < 4; nt++)
        acc[mt][nt] = __builtin_amdgcn_mfma_f32_16x16x32_bf16(
            af[mt], bfr[nt], acc[mt][nt], 0, 0, 0);
  }

  // Epilogue: lane's acc[mt][p] (gate) pairs with acc[mt][p+2] (hidden),
  // both for channel d = cb*64 + wc + 16*p + fl. C/D: col=fl, row=q*4+reg.
  float bg[2], bh[2];
#pragma unroll
  for (int p = 0; p < 2; p++) {
    const int d = cb * 64 + wc + 16 * p + fl;
    bg[p] = bias[d];
    bh[p] = bias[256 + d];
  }
#pragma unroll
  for (int mt = 0; mt < 4; mt++) {
#pragma unroll
    for (int p = 0; p < 2; p++) {
      const int d = cb * 64 + wc + 16 * p + fl;
      const long r0 = rowBase + wrow + 16 * mt + q * 4;
#pragma unroll
      for (int r = 0; r < 4; r++) {
        float a, v;
        av_from_gh(acc[mt][p][r] + bg[p], acc[mt][p + 2][r] + bh[p], a, v);
        AV[(r0 + r) * 256 + d] = pack_av(a, v);
      }
    }
  }
}

// ---------------------------------------------------------------------------
// Pass A: per-chunk summaries. block = (b, c); thread = channel d.
// ---------------------------------------------------------------------------
__global__ __launch_bounds__(256) void scan_partial(
    const unsigned* __restrict__ AV, float* __restrict__ Asum,
    float* __restrict__ Vsum) {
  const int d = threadIdx.x;
  const int c = blockIdx.x % NCHUNK;
  const int b = blockIdx.x / NCHUNK;
  float A = 1.f, H = 0.f;
  long base = ((long)b * Ss + (long)c * CLEN) * 256 + d;
#pragma unroll 8
  for (int t = 0; t < CLEN; t++) {
    const unsigned p = AV[base];
    const float a = __uint_as_float((p & 0xffffu) << 16);
    const float v = __uint_as_float(p & 0xffff0000u);
    A *= a;
    H = a * H + v;
    base += 256;
  }
  Asum[(long)blockIdx.x * 256 + d] = A;
  Vsum[(long)blockIdx.x * 256 + d] = H;
}

// ---------------------------------------------------------------------------
// Pass B: sequential combine across chunks. block = b; thread = d.
// ---------------------------------------------------------------------------
__global__ __launch_bounds__(256) void scan_combine(
    const float* __restrict__ Asum, const float* __restrict__ Vsum,
    float* __restrict__ Hin) {
  const int d = threadIdx.x;
  const int b = blockIdx.x;
  float h = 0.5f;  // h0 = g(0) = 0.5
#pragma unroll 8
  for (int c = 0; c < NCHUNK; c++) {
    const long i = ((long)b * NCHUNK + c) * 256 + d;
    Hin[i] = h;
    h = Asum[i] * h + Vsum[i];
  }
}

// ---------------------------------------------------------------------------
// Pass C: final scan. WRITE_BF16 ? bf16 hidden stream (layer0 -> X1)
//                                : f32 hidden stream (layer1 -> out)
// ---------------------------------------------------------------------------
template <bool WRITE_BF16>
__global__ __launch_bounds__(256) void scan_final(
    const unsigned* __restrict__ AV, const float* __restrict__ Hin,
    bf16* __restrict__ OutB, float* __restrict__ OutF,
    float* __restrict__ Hlast) {
  const int d = threadIdx.x;
  const int c = blockIdx.x % NCHUNK;
  const int b = blockIdx.x / NCHUNK;
  float h = Hin[(long)blockIdx.x * 256 + d];
  long base = ((long)b * Ss + (long)c * CLEN) * 256 + d;
#pragma unroll 8
  for (int t = 0; t < CLEN; t++) {
    const unsigned p = AV[base];
    const float a = __uint_as_float((p & 0xffffu) << 16);
    const float v = __uint_as_float(p & 0xffff0000u);
    h = a * h + v;
    if (WRITE_BF16)
      OutB[base] = __float2bfloat16(h);
    else
      OutF[base] = h;
    base += 256;
  }
  if (c == NCHUNK - 1) Hlast[b * 256 + d] = h;
}

// ---------------------------------------------------------------------------
extern "C" void kernel_launch(void* const* d_in, const int* in_sizes, int n_in,
                              void* d_out, int out_size, void* d_ws,
                              size_t ws_size, hipStream_t stream) {
  const float* x = (const float*)d_in[0];
  const float* W0f = (const float*)d_in[1];
  const float* b0 = (const float*)d_in[2];
  const float* W1f = (const float*)d_in[3];
  const float* b1 = (const float*)d_in[4];

  float* outF = (float*)d_out;              // out1 (f32), Mm*256 elements
  float* hlast = outF + (long)Mm * 256;     // h: (2,8,1,256) f32
  // d_out's first 32 MiB doubles as bf16 scratch for X1 (dead before the
  // final f32 out-write overwrites it; ordering is stream-sequential).
  bf16* Xb = (bf16*)d_out;

  char* ws = (char*)d_ws;
  unsigned* AV = (unsigned*)ws;                      // Mm*256 u32 = 64 MiB
  bf16* W0b = (bf16*)(ws + (long)Mm * 256 * 4);      // 512*256 bf16
  bf16* W1b = W0b + (long)Nn * Dd;
  float* Asum = (float*)(W1b + (long)Nn * Dd);       // 1 MiB each
  float* Vsum = Asum + (long)Bb * NCHUNK * 256;
  float* Hin = Vsum + (long)Bb * NCHUNK * 256;

  const dim3 gemmGrid(4, Mm / 128);  // cb fastest: 4 blocks share an X tile
  const dim3 blk(256);
  const dim3 scanGrid(Bb * NCHUNK);

  // Convert weights f32 -> bf16 (x is consumed as f32 by layer-0 GEMM)
  {
    const long n4w = (long)Nn * Dd / 4;
    cvt_f32_bf16<<<dim3((n4w + 255) / 256), blk, 0, stream>>>(W0f, W0b, n4w);
    cvt_f32_bf16<<<dim3((n4w + 255) / 256), blk, 0, stream>>>(W1f, W1b, n4w);
  }

  // Layer 0 (A = f32 x, converted in-register)
  gemm_av<true><<<gemmGrid, blk, 0, stream>>>(x, W0b, b0, AV);
  scan_partial<<<scanGrid, blk, 0, stream>>>(AV, Asum, Vsum);
  scan_combine<<<dim3(Bb), blk, 0, stream>>>(Asum, Vsum, Hin);
  scan_final<true><<<scanGrid, blk, 0, stream>>>(AV, Hin, Xb, nullptr, hlast);

  // Layer 1 (A = bf16 X1 in d_out scratch)
  gemm_av<false><<<gemmGrid, blk, 0, stream>>>(Xb, W1b, b1, AV);
  scan_partial<<<scanGrid, blk, 0, stream>>>(AV, Asum, Vsum);
  scan_combine<<<dim3(Bb), blk, 0, stream>>>(Asum, Vsum, Hin);
  scan_final<false><<<scanGrid, blk, 0, stream>>>(AV, Hin, nullptr, outF,
                                                  hlast + Bb * 256);
}

// Round 6
// 306.879 us; speedup vs baseline: 1.1696x; 1.1696x over previous
//
#include <hip/hip_runtime.h>
#include <hip/hip_bf16.h>

// Problem constants
#define Bb 8
#define Ss 8192
#define Dd 256             // DIN == DH == 256
#define Mm (Bb * Ss)       // 65536 rows
#define Nn 512             // 2*DH output cols of the GEMM
#define NCHUNK 128
#define CLEN (Ss / NCHUNK) // 64

typedef __hip_bfloat16 bf16;
typedef __attribute__((ext_vector_type(8))) short short8;
typedef __attribute__((ext_vector_type(4))) float f32x4;

// ---------------------------------------------------------------------------
// f32 -> bf16 convert (weights only)
// ---------------------------------------------------------------------------
__global__ __launch_bounds__(256) void cvt_f32_bf16(const float* __restrict__ in,
                                                    bf16* __restrict__ out,
                                                    long n4) {
  long i = (long)blockIdx.x * blockDim.x + threadIdx.x;
  if (i >= n4) return;
  const float4 v = ((const float4*)in)[i];
  union { ushort4 u; bf16 h[4]; } o;
  o.h[0] = __float2bfloat16(v.x);
  o.h[1] = __float2bfloat16(v.y);
  o.h[2] = __float2bfloat16(v.z);
  o.h[3] = __float2bfloat16(v.w);
  ((ushort4*)out)[i] = o.u;
}

// ---------------------------------------------------------------------------
// Pointwise: a = sigmoid(-gate), v = sigmoid(gate) * g(hidden)
// ---------------------------------------------------------------------------
__device__ __forceinline__ void av_from_gh(float gate, float hid, float& a,
                                           float& v) {
  gate = fminf(fmaxf(gate, -20.f), 20.f);
  float eg = __expf(gate);
  a = 1.f / (1.f + eg);   // sigmoid(-gate) = 1 - z
  float z = eg * a;       // sigmoid(gate)
  float gfun;
  if (hid >= 0.f) {
    gfun = hid + 0.5f;
  } else {
    float eh = __expf(fmaxf(hid, -20.f));
    gfun = eh / (1.f + eh);  // sigmoid(hid)
  }
  v = z * gfun;
}

__device__ __forceinline__ unsigned pack_av(float a, float v) {
  union { bf16 h[2]; unsigned u; } o;
  o.h[0] = __float2bfloat16(a);
  o.h[1] = __float2bfloat16(v);
  return o.u;
}

// ---------------------------------------------------------------------------
// Fused GEMM + bias + pointwise + per-chunk scan summaries.
//   block (cb, bt): rows [bt*128,+128) (= 2 scan chunks), paired channels
//   d in [cb*64,+64).  B (128 W-rows, all K) staged ONCE in LDS (64 KiB,
//   XOR-swizzled -> conflict-free ds_read_b128); A streamed from global with
//   an explicit 3-stage register pipeline; NO barriers in the K-loop.
//   Epilogue: packs (a,v) bf16x2 -> AV global, LDS-transposes, and 128
//   threads compute the 2 chunks' (prod a, local h) summaries.
// ---------------------------------------------------------------------------
template <bool F32A>
__global__ __launch_bounds__(256, 2) void gemm_av_fused(
    const void* __restrict__ Xv, const bf16* __restrict__ W,
    const float* __restrict__ bias, unsigned* __restrict__ AV,
    float* __restrict__ Asum, float* __restrict__ Vsum) {
  __shared__ __align__(16) char sm[65536];
  bf16* Bs = (bf16*)sm;        // [128 rows][256 k], 16B chunks XOR-swizzled
  unsigned* Ts = (unsigned*)sm; // overlay after K-loop: [128 rows][65] packed

  const int tid = threadIdx.x;
  const int w = tid >> 6;
  const int l = tid & 63;
  const int fl = l & 15;
  const int q = l >> 4;

  const int cb = blockIdx.x;          // paired-channel block 0..3
  const int bt = blockIdx.y;          // M-tile 0..511
  const long rowBase = (long)bt * 128;
  const int wrow = (w >> 1) * 64;
  const int wc = (w & 1) * 32;

  // ---- Stage B: 128 W-rows x 512B, per-lane 16B copies, XOR-swizzle chunks
#pragma unroll
  for (int i = 0; i < 16; i++) {
    const int idx = i * 256 + tid;    // 16B-chunk id, 0..4095
    const int rl = idx >> 5;          // LDS row 0..127
    const int c = idx & 31;           // chunk within row
    const int grow = (rl < 64) ? (cb * 64 + rl) : (192 + cb * 64 + rl);
    const int cst = (c & 24) | ((c & 7) ^ (rl & 7));
    *(short8*)(Bs + rl * 256 + cst * 8) =
        *(const short8*)(W + (long)grow * 256 + c * 8);
  }
  __syncthreads();

  f32x4 acc[4][4];
#pragma unroll
  for (int i = 0; i < 4; i++)
#pragma unroll
    for (int j = 0; j < 4; j++) acc[i][j] = (f32x4)0.0f;

  int brow[4];
  brow[0] = wc + fl;
  brow[1] = wc + 16 + fl;
  brow[2] = 64 + wc + fl;
  brow[3] = 64 + wc + 16 + fl;

  const bf16* Ab = (const bf16*)Xv + (rowBase + wrow + fl) * 256 + q * 8;
  const float* Af = (const float*)Xv + (rowBase + wrow + fl) * 256 + q * 8;

  auto ldA = [&](int mt, int ks) -> short8 {
    if constexpr (F32A) {
      const float* p = Af + (long)mt * 16 * 256 + ks * 32;
      const float4 u0 = ((const float4*)p)[0];
      const float4 u1 = ((const float4*)p)[1];
      const float vals[8] = {u0.x, u0.y, u0.z, u0.w, u1.x, u1.y, u1.z, u1.w};
      short8 r;
#pragma unroll
      for (int i = 0; i < 8; i++) {
        union { bf16 h; short s; } t;
        t.h = __float2bfloat16(vals[i]);
        r[i] = t.s;
      }
      return r;
    } else {
      return *(const short8*)(Ab + (long)mt * 16 * 256 + ks * 32);
    }
  };
  auto ldB = [&](int nt, int ks) -> short8 {
    const int r = brow[nt];
    const int ck = 4 * ks + q;
    const int cst = (ck & 24) | ((ck & 7) ^ (r & 7));
    return *(const short8*)(Bs + r * 256 + cst * 8);
  };

  // ---- K-loop: explicit register pipeline (A depth 2, B depth 1)
  short8 ap[3][4], bp[2][4];
#pragma unroll
  for (int mt = 0; mt < 4; mt++) ap[0][mt] = ldA(mt, 0);
#pragma unroll
  for (int mt = 0; mt < 4; mt++) ap[1][mt] = ldA(mt, 1);
#pragma unroll
  for (int nt = 0; nt < 4; nt++) bp[0][nt] = ldB(nt, 0);

#pragma unroll
  for (int ks = 0; ks < 8; ks++) {
    if (ks + 2 < 8) {
#pragma unroll
      for (int mt = 0; mt < 4; mt++) ap[(ks + 2) % 3][mt] = ldA(mt, ks + 2);
    }
    if (ks + 1 < 8) {
#pragma unroll
      for (int nt = 0; nt < 4; nt++) bp[(ks + 1) % 2][nt] = ldB(nt, ks + 1);
    }
#pragma unroll
    for (int mt = 0; mt < 4; mt++)
#pragma unroll
      for (int nt = 0; nt < 4; nt++)
        acc[mt][nt] = __builtin_amdgcn_mfma_f32_16x16x32_bf16(
            ap[ks % 3][mt], bp[ks % 2][nt], acc[mt][nt], 0, 0, 0);
  }

  // ---- Epilogue: bias + pointwise + pack; write AV global
  float bg[2], bh[2];
#pragma unroll
  for (int p = 0; p < 2; p++) {
    const int d = cb * 64 + wc + 16 * p + fl;
    bg[p] = bias[d];
    bh[p] = bias[256 + d];
  }
  unsigned pk[4][2][4];
#pragma unroll
  for (int mt = 0; mt < 4; mt++) {
#pragma unroll
    for (int p = 0; p < 2; p++) {
      const int d = cb * 64 + wc + 16 * p + fl;
      const long r0 = rowBase + wrow + 16 * mt + q * 4;
#pragma unroll
      for (int r = 0; r < 4; r++) {
        float a, v;
        av_from_gh(acc[mt][p][r] + bg[p], acc[mt][p + 2][r] + bh[p], a, v);
        pk[mt][p][r] = pack_av(a, v);
        AV[(r0 + r) * 256 + d] = pk[mt][p][r];
      }
    }
  }

  // ---- LDS transpose (overlay on Bs; all B reads are done)
  __syncthreads();
#pragma unroll
  for (int mt = 0; mt < 4; mt++)
#pragma unroll
    for (int p = 0; p < 2; p++)
#pragma unroll
      for (int r = 0; r < 4; r++)
        Ts[(wrow + 16 * mt + q * 4 + r) * 65 + wc + 16 * p + fl] =
            pk[mt][p][r];
  __syncthreads();

  // ---- Per-chunk scan summaries: 2 chunks x 64 channels = 128 tasks
  if (tid < 128) {
    const int chunk = tid >> 6;
    const int dd = tid & 63;
    float A = 1.f, H = 0.f;
#pragma unroll 8
    for (int t = 0; t < 64; t++) {
      const unsigned p = Ts[(chunk * 64 + t) * 65 + dd];
      const float a = __uint_as_float((p & 0xffffu) << 16);
      const float v = __uint_as_float(p & 0xffff0000u);
      A *= a;
      H = a * H + v;
    }
    const int b = bt >> 6;  // 64 M-tiles per batch
    const long cg = (long)b * NCHUNK + ((bt & 63) << 1) + chunk;
    Asum[cg * 256 + cb * 64 + dd] = A;
    Vsum[cg * 256 + cb * 64 + dd] = H;
  }
}

// ---------------------------------------------------------------------------
// Pass B: sequential combine across chunks. block = b; thread = d.
// ---------------------------------------------------------------------------
__global__ __launch_bounds__(256) void scan_combine(
    const float* __restrict__ Asum, const float* __restrict__ Vsum,
    float* __restrict__ Hin) {
  const int d = threadIdx.x;
  const int b = blockIdx.x;
  float h = 0.5f;  // h0 = g(0) = 0.5
#pragma unroll 8
  for (int c = 0; c < NCHUNK; c++) {
    const long i = ((long)b * NCHUNK + c) * 256 + d;
    Hin[i] = h;
    h = Asum[i] * h + Vsum[i];
  }
}

// ---------------------------------------------------------------------------
// Pass C: final scan. WRITE_BF16 ? bf16 hidden stream (layer0 -> X1)
//                                : f32 hidden stream (layer1 -> out)
// ---------------------------------------------------------------------------
template <bool WRITE_BF16>
__global__ __launch_bounds__(256) void scan_final(
    const unsigned* __restrict__ AV, const float* __restrict__ Hin,
    bf16* __restrict__ OutB, float* __restrict__ OutF,
    float* __restrict__ Hlast) {
  const int d = threadIdx.x;
  const int c = blockIdx.x % NCHUNK;
  const int b = blockIdx.x / NCHUNK;
  float h = Hin[(long)blockIdx.x * 256 + d];
  long base = ((long)b * Ss + (long)c * CLEN) * 256 + d;
#pragma unroll 8
  for (int t = 0; t < CLEN; t++) {
    const unsigned p = AV[base];
    const float a = __uint_as_float((p & 0xffffu) << 16);
    const float v = __uint_as_float(p & 0xffff0000u);
    h = a * h + v;
    if (WRITE_BF16)
      OutB[base] = __float2bfloat16(h);
    else
      OutF[base] = h;
    base += 256;
  }
  if (c == NCHUNK - 1) Hlast[b * 256 + d] = h;
}

// ---------------------------------------------------------------------------
extern "C" void kernel_launch(void* const* d_in, const int* in_sizes, int n_in,
                              void* d_out, int out_size, void* d_ws,
                              size_t ws_size, hipStream_t stream) {
  const float* x = (const float*)d_in[0];
  const float* W0f = (const float*)d_in[1];
  const float* b0 = (const float*)d_in[2];
  const float* W1f = (const float*)d_in[3];
  const float* b1 = (const float*)d_in[4];

  float* outF = (float*)d_out;              // out1 (f32), Mm*256 elements
  float* hlast = outF + (long)Mm * 256;     // h: (2,8,1,256) f32
  // d_out's first 32 MiB doubles as bf16 scratch for X1 (dead before the
  // final f32 out-write overwrites it; ordering is stream-sequential).
  bf16* Xb = (bf16*)d_out;

  char* ws = (char*)d_ws;
  unsigned* AV = (unsigned*)ws;                      // Mm*256 u32 = 64 MiB
  bf16* W0b = (bf16*)(ws + (long)Mm * 256 * 4);      // 512*256 bf16
  bf16* W1b = W0b + (long)Nn * Dd;
  float* Asum = (float*)(W1b + (long)Nn * Dd);       // 1 MiB each
  float* Vsum = Asum + (long)Bb * NCHUNK * 256;
  float* Hin = Vsum + (long)Bb * NCHUNK * 256;

  const dim3 gemmGrid(4, Mm / 128);  // cb fastest: 4 blocks share an X tile
  const dim3 blk(256);
  const dim3 scanGrid(Bb * NCHUNK);

  // Convert weights f32 -> bf16 (x is consumed as f32 by layer-0 GEMM)
  {
    const long n4w = (long)Nn * Dd / 4;
    cvt_f32_bf16<<<dim3((n4w + 255) / 256), blk, 0, stream>>>(W0f, W0b, n4w);
    cvt_f32_bf16<<<dim3((n4w + 255) / 256), blk, 0, stream>>>(W1f, W1b, n4w);
  }

  // Layer 0 (A = f32 x, converted in-register)
  gemm_av_fused<true><<<gemmGrid, blk, 0, stream>>>(x, W0b, b0, AV, Asum, Vsum);
  scan_combine<<<dim3(Bb), blk, 0, stream>>>(Asum, Vsum, Hin);
  scan_final<true><<<scanGrid, blk, 0, stream>>>(AV, Hin, Xb, nullptr, hlast);

  // Layer 1 (A = bf16 X1 in d_out scratch)
  gemm_av_fused<false><<<gemmGrid, blk, 0, stream>>>(Xb, W1b, b1, AV, Asum,
                                                     Vsum);
  scan_combine<<<dim3(Bb), blk, 0, stream>>>(Asum, Vsum, Hin);
  scan_final<false><<<scanGrid, blk, 0, stream>>>(AV, Hin, nullptr, outF,
                                                  hlast + Bb * 256);
}

// Round 7
// 271.147 us; speedup vs baseline: 1.3237x; 1.1318x over previous
//
#include <hip/hip_runtime.h>
#include <hip/hip_bf16.h>

// Problem constants
#define Bb 8
#define Ss 8192
#define Dd 256             // DIN == DH == 256
#define Mm (Bb * Ss)       // 65536 rows
#define Nn 512             // 2*DH output cols of the GEMM
#define NCHUNK 128
#define CLEN (Ss / NCHUNK) // 64

typedef __hip_bfloat16 bf16;
typedef __attribute__((ext_vector_type(8))) short short8;
typedef __attribute__((ext_vector_type(4))) float f32x4;

__device__ __forceinline__ void load_lds16(const void* g, void* l) {
  __builtin_amdgcn_global_load_lds(
      (const __attribute__((address_space(1))) void*)g,
      (__attribute__((address_space(3))) void*)l, 16, 0, 0);
}

// ---------------------------------------------------------------------------
// f32 -> bf16 convert (weights only)
// ---------------------------------------------------------------------------
__global__ __launch_bounds__(256) void cvt_f32_bf16(const float* __restrict__ in,
                                                    bf16* __restrict__ out,
                                                    long n4) {
  long i = (long)blockIdx.x * blockDim.x + threadIdx.x;
  if (i >= n4) return;
  const float4 v = ((const float4*)in)[i];
  union { ushort4 u; bf16 h[4]; } o;
  o.h[0] = __float2bfloat16(v.x);
  o.h[1] = __float2bfloat16(v.y);
  o.h[2] = __float2bfloat16(v.z);
  o.h[3] = __float2bfloat16(v.w);
  ((ushort4*)out)[i] = o.u;
}

// ---------------------------------------------------------------------------
// Pointwise: a = sigmoid(-gate), v = sigmoid(gate) * g(hidden)
// ---------------------------------------------------------------------------
__device__ __forceinline__ void av_from_gh(float gate, float hid, float& a,
                                           float& v) {
  gate = fminf(fmaxf(gate, -20.f), 20.f);
  float eg = __expf(gate);
  a = 1.f / (1.f + eg);   // sigmoid(-gate) = 1 - z
  float z = eg * a;       // sigmoid(gate)
  float gfun;
  if (hid >= 0.f) {
    gfun = hid + 0.5f;
  } else {
    float eh = __expf(fmaxf(hid, -20.f));
    gfun = eh / (1.f + eh);  // sigmoid(hid)
  }
  v = z * gfun;
}

__device__ __forceinline__ unsigned pack_av(float a, float v) {
  union { bf16 h[2]; unsigned u; } o;
  o.h[0] = __float2bfloat16(a);
  o.h[1] = __float2bfloat16(v);
  return o.u;
}

// ---------------------------------------------------------------------------
// Fused GEMM + bias + pointwise + per-chunk scan summaries.
// Double-buffered global_load_lds staging: DMA for K-step ks+1 issued BEFORE
// computing ks, so the barrier's vmcnt drain is mostly free.
// LDS chunks XOR-swizzled (lane fetches swizzled k-chunk) so fragment
// ds_read_b128s are conflict-free despite the forced lane*16B DMA landing.
//   block (cb, bt): rows [bt*128,+128) = 2 scan chunks; paired channels
//   d in [cb*64,+64): GEMM cols = gate d and hidden d+256.
// ---------------------------------------------------------------------------
template <bool F32A>
__global__ __launch_bounds__(256) void gemm_av_fused(
    const void* __restrict__ Xv, const bf16* __restrict__ W,
    const float* __restrict__ bias, unsigned* __restrict__ AV,
    float* __restrict__ Asum, float* __restrict__ Vsum) {
  constexpr int ABY = F32A ? 16384 : 8192;  // A-tile bytes per buffer
  __shared__ __align__(16) char sm[2 * ABY + 16384];
  char* Abuf0 = sm;
  char* Abuf1 = sm + ABY;
  bf16* Bbuf0 = (bf16*)(sm + 2 * ABY);
  bf16* Bbuf1 = (bf16*)(sm + 2 * ABY + 8192);
  unsigned* Ts = (unsigned*)sm;  // post-K-loop overlay: [64 t][65] u32

  const int tid = threadIdx.x;
  const int w = tid >> 6;
  const int l = tid & 63;
  const int fl = l & 15;
  const int q = l >> 4;

  const int cb = blockIdx.x;           // paired-channel block 0..3
  const int bt = blockIdx.y;           // M-tile 0..511
  const long rowBase = (long)bt * 128;
  const int wrow = (w >> 1) * 64;
  const int wc = (w & 1) * 32;

  const float* Xf = (const float*)Xv;
  const bf16* Xb = (const bf16*)Xv;

  // ---- staging (DMA). LDS chunk L holds global k-chunk (L&mask)^swizzle(row)
  auto stageA = [&](char* dst, int k0) {
    if constexpr (F32A) {
#pragma unroll
      for (int c = 0; c < 4; c++) {
        const int L = c * 256 + tid;
        const int row = L >> 3;                 // 0..127
        const int kc = (L & 7) ^ (row & 7);     // 4-float chunk
        load_lds16(Xf + (rowBase + row) * 256 + k0 + kc * 4,
                   dst + (c * 256 + w * 64) * 16);
      }
    } else {
#pragma unroll
      for (int c = 0; c < 2; c++) {
        const int L = c * 256 + tid;
        const int row = L >> 2;                        // 0..127
        const int kc = (L & 3) ^ ((row >> 1) & 3);     // 8-bf16 chunk
        load_lds16(Xb + (rowBase + row) * 256 + k0 + kc * 8,
                   dst + (c * 256 + w * 64) * 16);
      }
    }
  };
  auto stageB = [&](bf16* dst, int k0) {
#pragma unroll
    for (int c = 0; c < 2; c++) {
      const int L = c * 256 + tid;
      const int row = L >> 2;                      // 0..127
      const int kc = (L & 3) ^ ((row >> 1) & 3);
      const int grow = (row < 64) ? (cb * 64 + row) : (192 + cb * 64 + row);
      load_lds16(W + (long)grow * 256 + k0 + kc * 8,
                 (char*)dst + (c * 256 + w * 64) * 16);
    }
  };

  // ---- fragment reads (swizzled, conflict-free)
  auto fragA = [&](const char* buf, int mt) -> short8 {
    const int row = wrow + 16 * mt + fl;
    if constexpr (F32A) {
      const float* p = (const float*)buf + row * 32;
      const int k0c = (2 * q) ^ (row & 7);
      const int k1c = (2 * q + 1) ^ (row & 7);
      const float4 u0 = *(const float4*)(p + k0c * 4);
      const float4 u1 = *(const float4*)(p + k1c * 4);
      const float vals[8] = {u0.x, u0.y, u0.z, u0.w, u1.x, u1.y, u1.z, u1.w};
      short8 r;
#pragma unroll
      for (int i = 0; i < 8; i++) {
        union { bf16 h; short s; } t;
        t.h = __float2bfloat16(vals[i]);
        r[i] = t.s;
      }
      return r;
    } else {
      const int kc = q ^ ((row >> 1) & 3);
      return *(const short8*)((const bf16*)buf + row * 32 + kc * 8);
    }
  };
  auto fragB = [&](const bf16* buf, int nt) -> short8 {
    const int row =
        (nt < 2) ? (wc + 16 * nt + fl) : (64 + wc + 16 * (nt - 2) + fl);
    const int kc = q ^ ((row >> 1) & 3);
    return *(const short8*)(buf + row * 32 + kc * 8);
  };

  f32x4 acc[4][4];
#pragma unroll
  for (int i = 0; i < 4; i++)
#pragma unroll
    for (int j = 0; j < 4; j++) acc[i][j] = (f32x4)0.0f;

  // ---- K-loop: double-buffered, prefetch-then-compute
  stageA(Abuf0, 0);
  stageB(Bbuf0, 0);
  __syncthreads();
#pragma unroll
  for (int ks = 0; ks < 8; ks++) {
    const char* Ac = (ks & 1) ? Abuf1 : Abuf0;
    const bf16* Bc = (ks & 1) ? Bbuf1 : Bbuf0;
    if (ks < 7) {
      stageA((ks & 1) ? Abuf0 : Abuf1, (ks + 1) * 32);
      stageB((ks & 1) ? Bbuf0 : Bbuf1, (ks + 1) * 32);
    }
    short8 af[4], bf_[4];
#pragma unroll
    for (int mt = 0; mt < 4; mt++) af[mt] = fragA(Ac, mt);
#pragma unroll
    for (int nt = 0; nt < 4; nt++) bf_[nt] = fragB(Bc, nt);
#pragma unroll
    for (int mt = 0; mt < 4; mt++)
#pragma unroll
      for (int nt = 0; nt < 4; nt++)
        acc[mt][nt] = __builtin_amdgcn_mfma_f32_16x16x32_bf16(
            af[mt], bf_[nt], acc[mt][nt], 0, 0, 0);
    __syncthreads();
  }

  // ---- Epilogue: bias + pointwise + pack; AV global stores
  float bg[2], bh[2];
#pragma unroll
  for (int p = 0; p < 2; p++) {
    const int d = cb * 64 + wc + 16 * p + fl;
    bg[p] = bias[d];
    bh[p] = bias[256 + d];
  }
  unsigned pk[4][2][4];
#pragma unroll
  for (int mt = 0; mt < 4; mt++) {
#pragma unroll
    for (int p = 0; p < 2; p++) {
      const int d = cb * 64 + wc + 16 * p + fl;
      const long r0 = rowBase + wrow + 16 * mt + q * 4;
#pragma unroll
      for (int r = 0; r < 4; r++) {
        float a, v;
        av_from_gh(acc[mt][p][r] + bg[p], acc[mt][p + 2][r] + bh[p], a, v);
        pk[mt][p][r] = pack_av(a, v);
        AV[(r0 + r) * 256 + d] = pk[mt][p][r];
      }
    }
  }

  // ---- Per-chunk scan summaries, two 64-row halves through LDS transpose
#pragma unroll
  for (int h = 0; h < 2; h++) {
    if ((w >> 1) == h) {
#pragma unroll
      for (int mt = 0; mt < 4; mt++)
#pragma unroll
        for (int p = 0; p < 2; p++)
#pragma unroll
          for (int r = 0; r < 4; r++)
            Ts[(16 * mt + 4 * q + r) * 65 + wc + 16 * p + fl] = pk[mt][p][r];
    }
    __syncthreads();
    if (tid < 64) {
      float A = 1.f, H = 0.f;
#pragma unroll 8
      for (int t = 0; t < 64; t++) {
        const unsigned p = Ts[t * 65 + tid];
        const float a = __uint_as_float((p & 0xffffu) << 16);
        const float v = __uint_as_float(p & 0xffff0000u);
        A *= a;
        H = a * H + v;
      }
      const long cg = (long)(bt >> 6) * NCHUNK + ((bt & 63) << 1) + h;
      Asum[cg * 256 + cb * 64 + tid] = A;
      Vsum[cg * 256 + cb * 64 + tid] = H;
    }
    __syncthreads();
  }
}

// ---------------------------------------------------------------------------
// Pass B: sequential combine across chunks. block = b; thread = d.
// ---------------------------------------------------------------------------
__global__ __launch_bounds__(256) void scan_combine(
    const float* __restrict__ Asum, const float* __restrict__ Vsum,
    float* __restrict__ Hin) {
  const int d = threadIdx.x;
  const int b = blockIdx.x;
  float h = 0.5f;  // h0 = g(0) = 0.5
#pragma unroll 8
  for (int c = 0; c < NCHUNK; c++) {
    const long i = ((long)b * NCHUNK + c) * 256 + d;
    Hin[i] = h;
    h = Asum[i] * h + Vsum[i];
  }
}

// ---------------------------------------------------------------------------
// Pass C: final scan. WRITE_BF16 ? bf16 hidden stream (layer0 -> X1)
//                                : f32 hidden stream (layer1 -> out)
// ---------------------------------------------------------------------------
template <bool WRITE_BF16>
__global__ __launch_bounds__(256) void scan_final(
    const unsigned* __restrict__ AV, const float* __restrict__ Hin,
    bf16* __restrict__ OutB, float* __restrict__ OutF,
    float* __restrict__ Hlast) {
  const int d = threadIdx.x;
  const int c = blockIdx.x % NCHUNK;
  const int b = blockIdx.x / NCHUNK;
  float h = Hin[(long)blockIdx.x * 256 + d];
  long base = ((long)b * Ss + (long)c * CLEN) * 256 + d;
#pragma unroll 8
  for (int t = 0; t < CLEN; t++) {
    const unsigned p = AV[base];
    const float a = __uint_as_float((p & 0xffffu) << 16);
    const float v = __uint_as_float(p & 0xffff0000u);
    h = a * h + v;
    if (WRITE_BF16)
      OutB[base] = __float2bfloat16(h);
    else
      OutF[base] = h;
    base += 256;
  }
  if (c == NCHUNK - 1) Hlast[b * 256 + d] = h;
}

// ---------------------------------------------------------------------------
extern "C" void kernel_launch(void* const* d_in, const int* in_sizes, int n_in,
                              void* d_out, int out_size, void* d_ws,
                              size_t ws_size, hipStream_t stream) {
  const float* x = (const float*)d_in[0];
  const float* W0f = (const float*)d_in[1];
  const float* b0 = (const float*)d_in[2];
  const float* W1f = (const float*)d_in[3];
  const float* b1 = (const float*)d_in[4];

  float* outF = (float*)d_out;              // out1 (f32), Mm*256 elements
  float* hlast = outF + (long)Mm * 256;     // h: (2,8,1,256) f32
  // d_out's first 32 MiB doubles as bf16 scratch for X1 (dead before the
  // final f32 out-write overwrites it; ordering is stream-sequential).
  bf16* Xb = (bf16*)d_out;

  char* ws = (char*)d_ws;
  unsigned* AV = (unsigned*)ws;                      // Mm*256 u32 = 64 MiB
  bf16* W0b = (bf16*)(ws + (long)Mm * 256 * 4);      // 512*256 bf16
  bf16* W1b = W0b + (long)Nn * Dd;
  float* Asum = (float*)(W1b + (long)Nn * Dd);       // 1 MiB each
  float* Vsum = Asum + (long)Bb * NCHUNK * 256;
  float* Hin = Vsum + (long)Bb * NCHUNK * 256;

  const dim3 gemmGrid(4, Mm / 128);  // cb fastest: 4 blocks share an X tile
  const dim3 blk(256);
  const dim3 scanGrid(Bb * NCHUNK);

  // Convert weights f32 -> bf16 (x is consumed as f32 by layer-0 GEMM)
  {
    const long n4w = (long)Nn * Dd / 4;
    cvt_f32_bf16<<<dim3((n4w + 255) / 256), blk, 0, stream>>>(W0f, W0b, n4w);
    cvt_f32_bf16<<<dim3((n4w + 255) / 256), blk, 0, stream>>>(W1f, W1b, n4w);
  }

  // Layer 0 (A = f32 x, staged via DMA, converted after ds_read)
  gemm_av_fused<true><<<gemmGrid, blk, 0, stream>>>(x, W0b, b0, AV, Asum,
                                                    Vsum);
  scan_combine<<<dim3(Bb), blk, 0, stream>>>(Asum, Vsum, Hin);
  scan_final<true><<<scanGrid, blk, 0, stream>>>(AV, Hin, Xb, nullptr, hlast);

  // Layer 1 (A = bf16 X1 in d_out scratch)
  gemm_av_fused<false><<<gemmGrid, blk, 0, stream>>>(Xb, W1b, b1, AV, Asum,
                                                     Vsum);
  scan_combine<<<dim3(Bb), blk, 0, stream>>>(Asum, Vsum, Hin);
  scan_final<false><<<scanGrid, blk, 0, stream>>>(AV, Hin, nullptr, outF,
                                                  hlast + Bb * 256);
}